// Round 18
// baseline (354.453 us; speedup 1.0000x reference)
//
#include <hip/hip_runtime.h>
#include <hip/hip_bf16.h>

typedef __attribute__((ext_vector_type(4))) float fx4;
typedef __attribute__((ext_vector_type(8))) short bx8;
typedef __hip_bfloat16 bf16;

#define GLD16(dst, src)                                                        \
  __builtin_amdgcn_global_load_lds(                                            \
      (__attribute__((address_space(1))) void*)(src),                          \
      (__attribute__((address_space(3))) void*)(dst), 16, 0, 0)

__device__ inline float bf2f(short s_) {
  unsigned int u = ((unsigned int)(unsigned short)s_) << 16;
  float f;
  __builtin_memcpy(&f, &u, 4);
  return f;
}
__device__ inline short f2bf(float f) {
  __hip_bfloat16 h = __float2bfloat16(f);
  short r;
  __builtin_memcpy(&r, &h, 2);
  return r;
}

#define ATT_SL2E 0.12751740f  // (1/sqrt(128)) * log2(e), pre-folded into Q

// ---------------------------------------------------------------- cast x->bf16
__global__ __launch_bounds__(256) void k_cast(const float* __restrict__ in,
                                              bf16* __restrict__ out, int n4) {
  int i = blockIdx.x * 256 + threadIdx.x;
  if (i >= n4) return;
  float4 v = reinterpret_cast<const float4*>(in)[i];
  bf16 t[4] = {__float2bfloat16(v.x), __float2bfloat16(v.y),
               __float2bfloat16(v.z), __float2bfloat16(v.w)};
  reinterpret_cast<ushort4*>(out)[i] = *reinterpret_cast<ushort4*>(t);
}

// ------------------------------------------- transpose-cast fp32 RxC -> bf16 CxR
__global__ void k_tcast(const float* __restrict__ in, bf16* __restrict__ out,
                        int R, int C) {
  __shared__ float tile[32][33];
  int c0 = blockIdx.x * 32, r0 = blockIdx.y * 32;
  int tx = threadIdx.x, ty = threadIdx.y;
#pragma unroll
  for (int j = 0; j < 4; ++j)
    tile[ty + j * 8][tx] = in[(size_t)(r0 + ty + j * 8) * C + c0 + tx];
  __syncthreads();
#pragma unroll
  for (int j = 0; j < 4; ++j)
    out[(size_t)(c0 + ty + j * 8) * R + r0 + tx] =
        __float2bfloat16(tile[tx][ty + j * 8]);
}

// -------------------------------------- rope cos/sin table (interleaved float2)
__global__ __launch_bounds__(256) void k_ropetab(float2* __restrict__ csT) {
  int idx = blockIdx.x * 256 + threadIdx.x;  // 2048*64
  int t = idx >> 6, i = idx & 63;
  float inv = expf(-logf(10000.0f) * (float)i * (1.0f / 64.0f));
  float fr = (float)t * inv;
  csT[idx] = make_float2(cosf(fr), sinf(fr));
}

// --------------------- 128x128 GEMM (m97 structure, proven ~900 TF) ----------
// ROPE=1: compile-time column map col(n) = wc*32 + (n&1)*16 + (n>>1)*64 + lr
// -> each thread holds the rope pair (c, c+64) in acc[m][n], acc[m][n|2].
// V-blocks (n0>=4096): write DIRECTLY transposed to vT[b,h,d,s] (j -> s
// consecutive -> ushort4 stores); replaces the separate k_vtrans pass.
template <int ROPE>
__global__ __launch_bounds__(256) void k_gemm_bt(
    const bf16* __restrict__ A, const bf16* __restrict__ BT,
    const float* __restrict__ bias, void* __restrict__ Cp,
    bf16* __restrict__ vTout, int M, int N, int K, int out_bf16,
    const float2* __restrict__ csT) {
  __shared__ __align__(16) bf16 As[128 * 64];
  __shared__ __align__(16) bf16 Bs[128 * 64];
  const int tid = threadIdx.x;
  const int m0 = blockIdx.y * 128, n0 = blockIdx.x * 128;
  const int lane = tid & 63, w = tid >> 6;
  const int lr = lane & 15, lg = lane >> 4;
  const int wr = w >> 1, wc = w & 1;
  const int colbase = ROPE ? (wc * 32 + lr) : (wc * 64 + lr);
#define COLOF(n) (ROPE ? (colbase + ((n)&1) * 16 + ((n) >> 1) * 64) : (colbase + (n)*16))

  fx4 acc[4][4];
#pragma unroll
  for (int m = 0; m < 4; ++m)
#pragma unroll
    for (int n = 0; n < 4; ++n) acc[m][n] = (fx4)(0.0f);

  for (int kt = 0; kt < K; kt += 64) {
#pragma unroll
    for (int q = 0; q < 4; ++q) {
      const int slot = q * 256 + tid;
      const int row = slot >> 3, u = slot & 7;
      const int us = (u ^ (row & 7)) * 8;
      GLD16(&As[slot * 8], A + (size_t)(m0 + row) * K + kt + us);
      GLD16(&Bs[slot * 8], BT + (size_t)(n0 + row) * K + kt + us);
    }
    __syncthreads();
#pragma unroll
    for (int ks = 0; ks < 2; ++ks) {
      bx8 af[4], bf[4];
#pragma unroll
      for (int m = 0; m < 4; ++m) {
        const int r = wr * 64 + m * 16 + lr;
        const int u = ((ks * 4 + lg) ^ (lr & 7)) * 8;
        af[m] = *(const bx8*)&As[r * 64 + u];
      }
#pragma unroll
      for (int n = 0; n < 4; ++n) {
        const int r = COLOF(n);
        const int u = ((ks * 4 + lg) ^ (lr & 7)) * 8;
        bf[n] = *(const bx8*)&Bs[r * 64 + u];
      }
#pragma unroll
      for (int m = 0; m < 4; ++m)
#pragma unroll
        for (int n = 0; n < 4; ++n)
          acc[m][n] =
              __builtin_amdgcn_mfma_f32_16x16x32_bf16(af[m], bf[n], acc[m][n], 0, 0, 0);
    }
    __syncthreads();
  }

  float bv[4];
#pragma unroll
  for (int n = 0; n < 4; ++n) bv[n] = bias[n0 + COLOF(n)];

  if (ROPE) {
    bf16* Cb = (bf16*)Cp;
    if (n0 < 4096) {
      // register-pair rope: n in {0,1} holds col c, n|2 holds col c+64
      const float sc = (n0 < 2048) ? ATT_SL2E : 1.0f;  // q gets softmax scale
#pragma unroll
      for (int m = 0; m < 4; ++m)
#pragma unroll
        for (int n = 0; n < 2; ++n) {
          const int c = wc * 32 + n * 16 + lr;  // in [0,64)
#pragma unroll
          for (int j = 0; j < 4; ++j) {
            const int row = m0 + wr * 64 + m * 16 + lg * 4 + j;
            const int s = row & 2047;
            const float2 cs = csT[s * 64 + c];
            const float t1 = acc[m][n][j] + bv[n];
            const float t2 = acc[m][n | 2][j] + bv[n | 2];
            Cb[(size_t)row * N + n0 + c] =
                __float2bfloat16((t1 * cs.x - t2 * cs.y) * sc);
            Cb[(size_t)row * N + n0 + c + 64] =
                __float2bfloat16((t1 * cs.y + t2 * cs.x) * sc);
          }
        }
    } else {
      // V-block: write transposed to vT[(b*16+h)*128 + d][s], ushort4 over j
      const int h = (n0 - 4096) >> 7;      // head
      const int bq = m0 >> 11;             // batch (rows of a block share b)
      const int s0 = (m0 & 2047) + wr * 64;
#pragma unroll
      for (int m = 0; m < 4; ++m)
#pragma unroll
        for (int n = 0; n < 4; ++n) {
          const int d = COLOF(n);
          const int s = s0 + m * 16 + lg * 4;
          bf16 o4[4] = {__float2bfloat16(acc[m][n][0] + bv[n]),
                        __float2bfloat16(acc[m][n][1] + bv[n]),
                        __float2bfloat16(acc[m][n][2] + bv[n]),
                        __float2bfloat16(acc[m][n][3] + bv[n])};
          *(ushort4*)&vTout[((size_t)((bq * 16 + h) * 128 + d)) * 2048 + s] =
              *(ushort4*)o4;
        }
    }
    return;
  }

#pragma unroll
  for (int m = 0; m < 4; ++m)
#pragma unroll
    for (int n = 0; n < 4; ++n) {
      const int col = n0 + COLOF(n);
#pragma unroll
      for (int j = 0; j < 4; ++j) {
        const int row = m0 + wr * 64 + m * 16 + lg * 4 + j;
        const float v = acc[m][n][j] + bv[n];
        if (out_bf16)
          ((bf16*)Cp)[(size_t)row * N + col] = __float2bfloat16(v);
        else
          ((float*)Cp)[(size_t)row * N + col] = v;
      }
    }
#undef COLOF
}

// ------------------------------------------------------------- flash attention
// Split-KV, disjoint plain-store partials. KVBLK=64 dbuf + vmcnt(4).
// 48KB LDS -> 3 blocks/CU. Heavy blocks issued first (R14 lesson).
// T14: ks2=0 half of V prefetched to registers at tile top (hidden under
// QK^T + softmax); plain launch_bounds(256) so the +32 VGPRs don't hit the
// (256,2)-induced 128-reg cap (R3 lesson). ~156 regs = 3 waves/SIMD = LDS cap.
__global__ __launch_bounds__(256) void k_attn2(
    const bf16* __restrict__ qkv, const bf16* __restrict__ vT,
    bf16* __restrict__ ctx, float* __restrict__ O0, float* __restrict__ O1,
    float* __restrict__ l0, float* __restrict__ l1) {
  __shared__ __align__(16) bf16 Ks[2][64 * 128];
  __shared__ __align__(16) bf16 Ps[4][32 * 64];
  const int tid = threadIdx.x;
  const int lane = tid & 63, w = tid >> 6;
  const int lr = lane & 15, lg = lane >> 4;
  const int bid = blockIdx.x;
  const int u = bid >> 5, bh = bid & 31;
  const int b = bh >> 4, h = bh & 15;
  int qt, t0, t1;                    // t in units of 64 kv
  if (u < 8) {            // chunk0 of qt=8..15 : 16 tiles (kv 0..1023)
    qt = 8 + u; t0 = 0; t1 = 16;
  } else if (u < 16) {    // chunk1 of qt=15..8 : 2qt-14 tiles (kv 1024..)
    qt = 23 - u; t0 = 16; t1 = 2 * qt + 2;
  } else {                // full row qt=7..0 DESCENDING : 2qt+2 tiles
    qt = 23 - u; t0 = 0; t1 = 2 * qt + 2;
  }
  const int single = (u >= 16);
  const int nt = t1 - t0;

  const bf16* kbase = qkv + (size_t)b * 2048 * 6144 + 2048 + h * 128;
  const bf16* vbase = vT + (size_t)(b * 16 + h) * 128 * 2048;

  auto STAGE = [&](int bufi, int kt) {
    const int kv0 = kt * 64;
#pragma unroll
    for (int q = 0; q < 4; ++q) {
      const int slot = q * 256 + tid;
      const int row = slot >> 4, uu = slot & 15;
      GLD16(&Ks[bufi][slot * 8],
            kbase + (size_t)(kv0 + row) * 6144 + ((uu ^ (row & 15)) * 8));
    }
  };

  // Q fragments: 32 rows/wave (Q already has SL2E folded in)
  const bf16* qbase =
      qkv + (size_t)(b * 2048 + qt * 128 + w * 32) * 6144 + h * 128;
  bx8 qf[2][4];
#pragma unroll
  for (int m = 0; m < 2; ++m)
#pragma unroll
    for (int ks = 0; ks < 4; ++ks)
      qf[m][ks] = *(const bx8*)(qbase + (size_t)(m * 16 + lr) * 6144 + ks * 32 + lg * 8);

  bx8 vones;
#pragma unroll
  for (int e = 0; e < 8; ++e) vones[e] = (short)0x3F80;  // bf16 1.0

  fx4 oacc[2][8], lacc[2];
#pragma unroll
  for (int m = 0; m < 2; ++m) {
    lacc[m] = (fx4)(0.0f);
#pragma unroll
    for (int d = 0; d < 8; ++d) oacc[m][d] = (fx4)(0.0f);
  }

  const int qrow0 = qt * 128 + w * 32;

  STAGE(0, t0);
  for (int i = 0; i < nt; ++i) {
    const int kt = t0 + i;
    const int cur = i & 1;
    if (i + 1 < nt) {
      STAGE(cur ^ 1, kt + 1);
      asm volatile("s_waitcnt vmcnt(4)" ::: "memory");
    } else {
      asm volatile("s_waitcnt vmcnt(0)" ::: "memory");
    }
    __builtin_amdgcn_s_barrier();
    asm volatile("" ::: "memory");

    const int kv0 = kt * 64;
    if (kv0 <= qrow0 + 31) {  // else wave fully masked (barriers stay outside)
      // ---- T14 prefetch: ks2=0 half of V into registers (consumed in PV)
      bx8 vpre[8];
#pragma unroll
      for (int dn = 0; dn < 8; ++dn)
        vpre[dn] =
            *(const bx8*)(vbase + (size_t)(dn * 16 + lr) * 2048 + kv0 + lg * 8);

      // ---- QK^T over this 64-kv tile (result already in log2 units)
      fx4 sacc[2][4];
#pragma unroll
      for (int n = 0; n < 4; ++n) {
        sacc[0][n] = (fx4)(0.0f);
        sacc[1][n] = (fx4)(0.0f);
      }
      __builtin_amdgcn_s_setprio(1);
#pragma unroll
      for (int n = 0; n < 4; ++n) {
        const int r = n * 16 + lr;
#pragma unroll
        for (int ks = 0; ks < 4; ++ks) {
          const bx8 kf = *(const bx8*)&Ks[cur][r * 128 + (((ks * 4 + lg) ^ lr) * 8)];
          sacc[0][n] =
              __builtin_amdgcn_mfma_f32_16x16x32_bf16(qf[0][ks], kf, sacc[0][n], 0, 0, 0);
          sacc[1][n] =
              __builtin_amdgcn_mfma_f32_16x16x32_bf16(qf[1][ks], kf, sacc[1][n], 0, 0, 0);
        }
      }
      __builtin_amdgcn_s_setprio(0);

      // ---- static-max softmax: p = exp2(min(v, 60)); masked -> 0
      const bool needmask = (kv0 + 63) > qrow0;  // wave-uniform
#pragma unroll
      for (int n = 0; n < 4; ++n) {
        const int kvi = kv0 + n * 16 + lr;
#pragma unroll
        for (int m = 0; m < 2; ++m)
#pragma unroll
          for (int j = 0; j < 4; ++j) {
            float v = sacc[m][n][j];
            if (needmask) {
              const int qi = qrow0 + m * 16 + lg * 4 + j;
              if (kvi > qi) v = -200.0f;
            }
            const float p = exp2f(fminf(v, 60.0f));
            const int r = m * 16 + lg * 4 + j, c = n * 16 + lr;
            const int c2 = (c & 7) | (((c >> 3) ^ (r & 7)) << 3);
            Ps[w][r * 64 + c2] = __float2bfloat16(p);
          }
      }

      // ---- PV: ks2=0 from prefetched regs, ks2=1 inline (overlaps MFMAs)
      __builtin_amdgcn_s_setprio(1);
      {
        const int uu = (lg ^ (lr & 7)) * 8;
        const bx8 pf0 = *(const bx8*)&Ps[w][(0 * 16 + lr) * 64 + uu];
        const bx8 pf1 = *(const bx8*)&Ps[w][(1 * 16 + lr) * 64 + uu];
        lacc[0] = __builtin_amdgcn_mfma_f32_16x16x32_bf16(pf0, vones, lacc[0], 0, 0, 0);
        lacc[1] = __builtin_amdgcn_mfma_f32_16x16x32_bf16(pf1, vones, lacc[1], 0, 0, 0);
#pragma unroll
        for (int dn = 0; dn < 8; ++dn) {
          oacc[0][dn] =
              __builtin_amdgcn_mfma_f32_16x16x32_bf16(pf0, vpre[dn], oacc[0][dn], 0, 0, 0);
          oacc[1][dn] =
              __builtin_amdgcn_mfma_f32_16x16x32_bf16(pf1, vpre[dn], oacc[1][dn], 0, 0, 0);
        }
      }
      {
        const int uu = ((4 + lg) ^ (lr & 7)) * 8;
        const bx8 pf0 = *(const bx8*)&Ps[w][(0 * 16 + lr) * 64 + uu];
        const bx8 pf1 = *(const bx8*)&Ps[w][(1 * 16 + lr) * 64 + uu];
        lacc[0] = __builtin_amdgcn_mfma_f32_16x16x32_bf16(pf0, vones, lacc[0], 0, 0, 0);
        lacc[1] = __builtin_amdgcn_mfma_f32_16x16x32_bf16(pf1, vones, lacc[1], 0, 0, 0);
#pragma unroll
        for (int dn = 0; dn < 8; ++dn) {
          const bx8 vf = *(const bx8*)(vbase + (size_t)(dn * 16 + lr) * 2048 + kv0 +
                                       32 + lg * 8);
          oacc[0][dn] =
              __builtin_amdgcn_mfma_f32_16x16x32_bf16(pf0, vf, oacc[0][dn], 0, 0, 0);
          oacc[1][dn] =
              __builtin_amdgcn_mfma_f32_16x16x32_bf16(pf1, vf, oacc[1][dn], 0, 0, 0);
        }
      }
      __builtin_amdgcn_s_setprio(0);
    }
    __builtin_amdgcn_s_barrier();  // all waves done reading Ks[cur]
    asm volatile("" ::: "memory");
  }

  if (single) {
    float rl[2][4];
#pragma unroll
    for (int m = 0; m < 2; ++m)
#pragma unroll
      for (int j = 0; j < 4; ++j) rl[m][j] = 1.0f / lacc[m][j];
#pragma unroll
    for (int m = 0; m < 2; ++m)
#pragma unroll
      for (int dn = 0; dn < 8; ++dn)
#pragma unroll
        for (int j = 0; j < 4; ++j) {
          const int row = qt * 128 + w * 32 + m * 16 + lg * 4 + j;
          ctx[(size_t)(b * 2048 + row) * 2048 + h * 128 + dn * 16 + lr] =
              __float2bfloat16(oacc[m][dn][j] * rl[m][j]);
        }
  } else {
    // disjoint plain-store partials (each element written exactly once)
    float* Op = (u < 8) ? O0 : O1;
    float* lp = (u < 8) ? l0 : l1;
    float* obase =
        Op + (((size_t)(b * 16 + h)) * 1024 + (qt * 128 - 1024 + w * 32)) * 128;
#pragma unroll
    for (int m = 0; m < 2; ++m)
#pragma unroll
      for (int dn = 0; dn < 8; ++dn)
#pragma unroll
        for (int j = 0; j < 4; ++j)
          obase[(m * 16 + lg * 4 + j) * 128 + dn * 16 + lr] = oacc[m][dn][j];
    if (lr == 0) {
      float* lbase =
          lp + ((size_t)(b * 16 + h)) * 1024 + (qt * 128 - 1024 + w * 32);
#pragma unroll
      for (int m = 0; m < 2; ++m)
#pragma unroll
        for (int j = 0; j < 4; ++j) lbase[m * 16 + lg * 4 + j] = lacc[m][j];
    }
  }
}

// ----------------------- combine split rows: ctx = (O0+O1)/(l0+l1), s>=1024
__global__ __launch_bounds__(256) void k_comb(const float* __restrict__ O0,
                                              const float* __restrict__ O1,
                                              const float* __restrict__ l0,
                                              const float* __restrict__ l1,
                                              bf16* __restrict__ ctx) {
  const int idx = blockIdx.x * 256 + threadIdx.x;  // 524288 threads x 8 floats
  const size_t base = (size_t)idx * 8;
  const size_t rowi = base >> 7;  // (b*16+h)*1024 + (s-1024)
  const float rl = 1.0f / (l0[rowi] + l1[rowi]);
  const float4 a0 = *(const float4*)&O0[base];
  const float4 b0 = *(const float4*)&O0[base + 4];
  const float4 a1 = *(const float4*)&O1[base];
  const float4 b1 = *(const float4*)&O1[base + 4];
  const int d = (int)(base & 127);
  const int s = (int)(rowi & 1023);
  const int bh = (int)(rowi >> 10);
  const int b = bh >> 4, h = bh & 15;
  bf16 o[8] = {__float2bfloat16((a0.x + a1.x) * rl), __float2bfloat16((a0.y + a1.y) * rl),
               __float2bfloat16((a0.z + a1.z) * rl), __float2bfloat16((a0.w + a1.w) * rl),
               __float2bfloat16((b0.x + b1.x) * rl), __float2bfloat16((b0.y + b1.y) * rl),
               __float2bfloat16((b0.z + b1.z) * rl), __float2bfloat16((b0.w + b1.w) * rl)};
  bf16* p = ctx + (size_t)(b * 2048 + 1024 + s) * 2048 + h * 128 + d;
  *(ushort4*)p = *(ushort4*)o;
  *(ushort4*)(p + 4) = *(ushort4*)(o + 4);
}

// ------------------------------------------------------------------- launcher
extern "C" void kernel_launch(void* const* d_in, const int* in_sizes, int n_in,
                              void* d_out, int out_size, void* d_ws, size_t ws_size,
                              hipStream_t stream) {
  const float* x = (const float*)d_in[0];
  const float* Wqkv = (const float*)d_in[1];
  const float* bqkv = (const float*)d_in[2];
  const float* Wout = (const float*)d_in[3];
  const float* bout = (const float*)d_in[4];
  float* out = (float*)d_out;

  char* ws = (char*)d_ws;
  bf16* xb    = (bf16*)(ws + 0);          // 16 MiB (dead after QKV GEMM)
  bf16* wqkvT = (bf16*)(ws + 16777216);   // 24 MiB (dead after QKV GEMM)
  bf16* woutT = (bf16*)(ws + 41943040);   // 8 MiB
  bf16* qkvb  = (bf16*)(ws + 50331648);   // 48 MiB (V region unused now)
  bf16* vTb   = (bf16*)(ws + 100663296);  // 16 MiB
  bf16* ctxb  = (bf16*)(ws + 117440512);  // 16 MiB
  float2* csT = (float2*)(ws + 134217728); // 1 MiB interleaved cos/sin
  // split-KV partials overlap the dead xb/wqkvT regions:
  float* O0 = (float*)(ws + 0);               // 16 MiB
  float* O1 = (float*)(ws + 16777216);        // 16 MiB
  float* l0 = (float*)(ws + 33554432);        // 128 KiB
  float* l1 = (float*)(ws + 33685504);        // 128 KiB

  k_ropetab<<<512, 256, 0, stream>>>(csT);
  k_cast<<<8192, 256, 0, stream>>>(x, xb, 2097152);
  k_tcast<<<dim3(192, 64), dim3(32, 8), 0, stream>>>(Wqkv, wqkvT, 2048, 6144);
  k_tcast<<<dim3(64, 64), dim3(32, 8), 0, stream>>>(Wout, woutT, 2048, 2048);
  // QKV = x @ Wqkv + b: register-pair RoPE epilogue; V written transposed
  k_gemm_bt<1><<<dim3(48, 32), 256, 0, stream>>>(xb, wqkvT, bqkv, qkvb, vTb,
                                                 4096, 6144, 2048, 1, csT);
  // split-KV flash attention: 768 blocks, heavy-first issue order
  k_attn2<<<768, 256, 0, stream>>>(qkvb, vTb, ctxb, O0, O1, l0, l1);
  k_comb<<<2048, 256, 0, stream>>>(O0, O1, l0, l1, ctxb);
  // out = ctx @ Wout + bout (fp32 out)
  k_gemm_bt<0><<<dim3(16, 32), 256, 0, stream>>>(ctxb, woutT, bout, out, nullptr,
                                                 4096, 2048, 2048, 0, csT);
}

// Round 19
// 304.752 us; speedup vs baseline: 1.1631x; 1.1631x over previous
//
#include <hip/hip_runtime.h>
#include <hip/hip_bf16.h>

typedef __attribute__((ext_vector_type(4))) float fx4;
typedef __attribute__((ext_vector_type(8))) short bx8;
typedef __hip_bfloat16 bf16;

#define GLD16(dst, src)                                                        \
  __builtin_amdgcn_global_load_lds(                                            \
      (__attribute__((address_space(1))) void*)(src),                          \
      (__attribute__((address_space(3))) void*)(dst), 16, 0, 0)

__device__ inline float bf2f(short s_) {
  unsigned int u = ((unsigned int)(unsigned short)s_) << 16;
  float f;
  __builtin_memcpy(&f, &u, 4);
  return f;
}
__device__ inline short f2bf(float f) {
  __hip_bfloat16 h = __float2bfloat16(f);
  short r;
  __builtin_memcpy(&r, &h, 2);
  return r;
}

#define ATT_SL2E 0.12751740f  // (1/sqrt(128)) * log2(e), pre-folded into Q

// ---------------------------------------------------------------- cast x->bf16
__global__ __launch_bounds__(256) void k_cast(const float* __restrict__ in,
                                              bf16* __restrict__ out, int n4) {
  int i = blockIdx.x * 256 + threadIdx.x;
  if (i >= n4) return;
  float4 v = reinterpret_cast<const float4*>(in)[i];
  bf16 t[4] = {__float2bfloat16(v.x), __float2bfloat16(v.y),
               __float2bfloat16(v.z), __float2bfloat16(v.w)};
  reinterpret_cast<ushort4*>(out)[i] = *reinterpret_cast<ushort4*>(t);
}

// ------------------------------------------- transpose-cast fp32 RxC -> bf16 CxR
__global__ void k_tcast(const float* __restrict__ in, bf16* __restrict__ out,
                        int R, int C) {
  __shared__ float tile[32][33];
  int c0 = blockIdx.x * 32, r0 = blockIdx.y * 32;
  int tx = threadIdx.x, ty = threadIdx.y;
#pragma unroll
  for (int j = 0; j < 4; ++j)
    tile[ty + j * 8][tx] = in[(size_t)(r0 + ty + j * 8) * C + c0 + tx];
  __syncthreads();
#pragma unroll
  for (int j = 0; j < 4; ++j)
    out[(size_t)(c0 + ty + j * 8) * R + r0 + tx] =
        __float2bfloat16(tile[tx][ty + j * 8]);
}

// -------------------------------------- rope cos/sin table (interleaved float2)
__global__ __launch_bounds__(256) void k_ropetab(float2* __restrict__ csT) {
  int idx = blockIdx.x * 256 + threadIdx.x;  // 2048*64
  int t = idx >> 6, i = idx & 63;
  float inv = expf(-logf(10000.0f) * (float)i * (1.0f / 64.0f));
  float fr = (float)t * inv;
  csT[idx] = make_float2(cosf(fr), sinf(fr));
}

// --------------------- 128x128 GEMM (m97 structure, proven ~900 TF) ----------
// ROPE=1: compile-time column map col(n) = wc*32 + (n&1)*16 + (n>>1)*64 + lr
// -> each thread holds the rope pair (c, c+64) in acc[m][n], acc[m][n|2].
// V-blocks (n0>=4096): write DIRECTLY transposed to vT[b,h,d,s] (j -> s
// consecutive -> ushort4 stores); replaces the separate k_vtrans pass.
template <int ROPE>
__global__ __launch_bounds__(256) void k_gemm_bt(
    const bf16* __restrict__ A, const bf16* __restrict__ BT,
    const float* __restrict__ bias, void* __restrict__ Cp,
    bf16* __restrict__ vTout, int M, int N, int K, int out_bf16,
    const float2* __restrict__ csT) {
  __shared__ __align__(16) bf16 As[128 * 64];
  __shared__ __align__(16) bf16 Bs[128 * 64];
  const int tid = threadIdx.x;
  const int m0 = blockIdx.y * 128, n0 = blockIdx.x * 128;
  const int lane = tid & 63, w = tid >> 6;
  const int lr = lane & 15, lg = lane >> 4;
  const int wr = w >> 1, wc = w & 1;
  const int colbase = ROPE ? (wc * 32 + lr) : (wc * 64 + lr);
#define COLOF(n) (ROPE ? (colbase + ((n)&1) * 16 + ((n) >> 1) * 64) : (colbase + (n)*16))

  fx4 acc[4][4];
#pragma unroll
  for (int m = 0; m < 4; ++m)
#pragma unroll
    for (int n = 0; n < 4; ++n) acc[m][n] = (fx4)(0.0f);

  for (int kt = 0; kt < K; kt += 64) {
#pragma unroll
    for (int q = 0; q < 4; ++q) {
      const int slot = q * 256 + tid;
      const int row = slot >> 3, u = slot & 7;
      const int us = (u ^ (row & 7)) * 8;
      GLD16(&As[slot * 8], A + (size_t)(m0 + row) * K + kt + us);
      GLD16(&Bs[slot * 8], BT + (size_t)(n0 + row) * K + kt + us);
    }
    __syncthreads();
#pragma unroll
    for (int ks = 0; ks < 2; ++ks) {
      bx8 af[4], bf[4];
#pragma unroll
      for (int m = 0; m < 4; ++m) {
        const int r = wr * 64 + m * 16 + lr;
        const int u = ((ks * 4 + lg) ^ (lr & 7)) * 8;
        af[m] = *(const bx8*)&As[r * 64 + u];
      }
#pragma unroll
      for (int n = 0; n < 4; ++n) {
        const int r = COLOF(n);
        const int u = ((ks * 4 + lg) ^ (lr & 7)) * 8;
        bf[n] = *(const bx8*)&Bs[r * 64 + u];
      }
#pragma unroll
      for (int m = 0; m < 4; ++m)
#pragma unroll
        for (int n = 0; n < 4; ++n)
          acc[m][n] =
              __builtin_amdgcn_mfma_f32_16x16x32_bf16(af[m], bf[n], acc[m][n], 0, 0, 0);
    }
    __syncthreads();
  }

  float bv[4];
#pragma unroll
  for (int n = 0; n < 4; ++n) bv[n] = bias[n0 + COLOF(n)];

  if (ROPE) {
    bf16* Cb = (bf16*)Cp;
    if (n0 < 4096) {
      // register-pair rope: n in {0,1} holds col c, n|2 holds col c+64
      const float sc = (n0 < 2048) ? ATT_SL2E : 1.0f;  // q gets softmax scale
#pragma unroll
      for (int m = 0; m < 4; ++m)
#pragma unroll
        for (int n = 0; n < 2; ++n) {
          const int c = wc * 32 + n * 16 + lr;  // in [0,64)
#pragma unroll
          for (int j = 0; j < 4; ++j) {
            const int row = m0 + wr * 64 + m * 16 + lg * 4 + j;
            const int s = row & 2047;
            const float2 cs = csT[s * 64 + c];
            const float t1 = acc[m][n][j] + bv[n];
            const float t2 = acc[m][n | 2][j] + bv[n | 2];
            Cb[(size_t)row * N + n0 + c] =
                __float2bfloat16((t1 * cs.x - t2 * cs.y) * sc);
            Cb[(size_t)row * N + n0 + c + 64] =
                __float2bfloat16((t1 * cs.y + t2 * cs.x) * sc);
          }
        }
    } else {
      // V-block: write transposed to vT[(b*16+h)*128 + d][s], ushort4 over j
      const int h = (n0 - 4096) >> 7;      // head
      const int bq = m0 >> 11;             // batch (rows of a block share b)
      const int s0 = (m0 & 2047) + wr * 64;
#pragma unroll
      for (int m = 0; m < 4; ++m)
#pragma unroll
        for (int n = 0; n < 4; ++n) {
          const int d = COLOF(n);
          const int s = s0 + m * 16 + lg * 4;
          bf16 o4[4] = {__float2bfloat16(acc[m][n][0] + bv[n]),
                        __float2bfloat16(acc[m][n][1] + bv[n]),
                        __float2bfloat16(acc[m][n][2] + bv[n]),
                        __float2bfloat16(acc[m][n][3] + bv[n])};
          *(ushort4*)&vTout[((size_t)((bq * 16 + h) * 128 + d)) * 2048 + s] =
              *(ushort4*)o4;
        }
    }
    return;
  }

#pragma unroll
  for (int m = 0; m < 4; ++m)
#pragma unroll
    for (int n = 0; n < 4; ++n) {
      const int col = n0 + COLOF(n);
#pragma unroll
      for (int j = 0; j < 4; ++j) {
        const int row = m0 + wr * 64 + m * 16 + lg * 4 + j;
        const float v = acc[m][n][j] + bv[n];
        if (out_bf16)
          ((bf16*)Cp)[(size_t)row * N + col] = __float2bfloat16(v);
        else
          ((float*)Cp)[(size_t)row * N + col] = v;
      }
    }
#undef COLOF
}

// ------------------------------------------------------------- flash attention
// Split-KV, disjoint plain-store partials. KVBLK=64 dbuf + vmcnt(4).
// 48KB LDS -> 3 blocks/CU. Heavy blocks issued first (R14 lesson). Inline V
// loads in PV (R17 lesson: register prefetch breaks the compiler's per-pair
// load/MFMA interleave -> -70%; keep the compiler's schedule).
__global__ __launch_bounds__(256, 2) void k_attn2(
    const bf16* __restrict__ qkv, const bf16* __restrict__ vT,
    bf16* __restrict__ ctx, float* __restrict__ O0, float* __restrict__ O1,
    float* __restrict__ l0, float* __restrict__ l1) {
  __shared__ __align__(16) bf16 Ks[2][64 * 128];
  __shared__ __align__(16) bf16 Ps[4][32 * 64];
  const int tid = threadIdx.x;
  const int lane = tid & 63, w = tid >> 6;
  const int lr = lane & 15, lg = lane >> 4;
  const int bid = blockIdx.x;
  const int u = bid >> 5, bh = bid & 31;
  const int b = bh >> 4, h = bh & 15;
  int qt, t0, t1;                    // t in units of 64 kv
  if (u < 8) {            // chunk0 of qt=8..15 : 16 tiles (kv 0..1023)
    qt = 8 + u; t0 = 0; t1 = 16;
  } else if (u < 16) {    // chunk1 of qt=15..8 : 2qt-14 tiles (kv 1024..)
    qt = 23 - u; t0 = 16; t1 = 2 * qt + 2;
  } else {                // full row qt=7..0 DESCENDING : 2qt+2 tiles
    qt = 23 - u; t0 = 0; t1 = 2 * qt + 2;
  }
  const int single = (u >= 16);
  const int nt = t1 - t0;

  const bf16* kbase = qkv + (size_t)b * 2048 * 6144 + 2048 + h * 128;
  const bf16* vbase = vT + (size_t)(b * 16 + h) * 128 * 2048;

  auto STAGE = [&](int bufi, int kt) {
    const int kv0 = kt * 64;
#pragma unroll
    for (int q = 0; q < 4; ++q) {
      const int slot = q * 256 + tid;
      const int row = slot >> 4, uu = slot & 15;
      GLD16(&Ks[bufi][slot * 8],
            kbase + (size_t)(kv0 + row) * 6144 + ((uu ^ (row & 15)) * 8));
    }
  };

  // Q fragments: 32 rows/wave (Q already has SL2E folded in)
  const bf16* qbase =
      qkv + (size_t)(b * 2048 + qt * 128 + w * 32) * 6144 + h * 128;
  bx8 qf[2][4];
#pragma unroll
  for (int m = 0; m < 2; ++m)
#pragma unroll
    for (int ks = 0; ks < 4; ++ks)
      qf[m][ks] = *(const bx8*)(qbase + (size_t)(m * 16 + lr) * 6144 + ks * 32 + lg * 8);

  bx8 vones;
#pragma unroll
  for (int e = 0; e < 8; ++e) vones[e] = (short)0x3F80;  // bf16 1.0

  fx4 oacc[2][8], lacc[2];
#pragma unroll
  for (int m = 0; m < 2; ++m) {
    lacc[m] = (fx4)(0.0f);
#pragma unroll
    for (int d = 0; d < 8; ++d) oacc[m][d] = (fx4)(0.0f);
  }

  const int qrow0 = qt * 128 + w * 32;

  STAGE(0, t0);
  for (int i = 0; i < nt; ++i) {
    const int kt = t0 + i;
    const int cur = i & 1;
    if (i + 1 < nt) {
      STAGE(cur ^ 1, kt + 1);
      asm volatile("s_waitcnt vmcnt(4)" ::: "memory");
    } else {
      asm volatile("s_waitcnt vmcnt(0)" ::: "memory");
    }
    __builtin_amdgcn_s_barrier();
    asm volatile("" ::: "memory");

    const int kv0 = kt * 64;
    if (kv0 <= qrow0 + 31) {  // else wave fully masked (barriers stay outside)
      // ---- QK^T over this 64-kv tile (result already in log2 units)
      fx4 sacc[2][4];
#pragma unroll
      for (int n = 0; n < 4; ++n) {
        sacc[0][n] = (fx4)(0.0f);
        sacc[1][n] = (fx4)(0.0f);
      }
      __builtin_amdgcn_s_setprio(1);
#pragma unroll
      for (int n = 0; n < 4; ++n) {
        const int r = n * 16 + lr;
#pragma unroll
        for (int ks = 0; ks < 4; ++ks) {
          const bx8 kf = *(const bx8*)&Ks[cur][r * 128 + (((ks * 4 + lg) ^ lr) * 8)];
          sacc[0][n] =
              __builtin_amdgcn_mfma_f32_16x16x32_bf16(qf[0][ks], kf, sacc[0][n], 0, 0, 0);
          sacc[1][n] =
              __builtin_amdgcn_mfma_f32_16x16x32_bf16(qf[1][ks], kf, sacc[1][n], 0, 0, 0);
        }
      }
      __builtin_amdgcn_s_setprio(0);

      // ---- static-max softmax: p = exp2(min(v, 60)); masked -> 0
      const bool needmask = (kv0 + 63) > qrow0;  // wave-uniform
#pragma unroll
      for (int n = 0; n < 4; ++n) {
        const int kvi = kv0 + n * 16 + lr;
#pragma unroll
        for (int m = 0; m < 2; ++m)
#pragma unroll
          for (int j = 0; j < 4; ++j) {
            float v = sacc[m][n][j];
            if (needmask) {
              const int qi = qrow0 + m * 16 + lg * 4 + j;
              if (kvi > qi) v = -200.0f;
            }
            const float p = exp2f(fminf(v, 60.0f));
            const int r = m * 16 + lg * 4 + j, c = n * 16 + lr;
            const int c2 = (c & 7) | (((c >> 3) ^ (r & 7)) << 3);
            Ps[w][r * 64 + c2] = __float2bfloat16(p);
          }
      }

      // ---- PV (V direct from global, L2-resident) + row-sum via ones-MFMA
      __builtin_amdgcn_s_setprio(1);
#pragma unroll
      for (int ks2 = 0; ks2 < 2; ++ks2) {
        const int uu = ((ks2 * 4 + lg) ^ (lr & 7)) * 8;
        const bx8 pf0 = *(const bx8*)&Ps[w][(0 * 16 + lr) * 64 + uu];
        const bx8 pf1 = *(const bx8*)&Ps[w][(1 * 16 + lr) * 64 + uu];
        lacc[0] = __builtin_amdgcn_mfma_f32_16x16x32_bf16(pf0, vones, lacc[0], 0, 0, 0);
        lacc[1] = __builtin_amdgcn_mfma_f32_16x16x32_bf16(pf1, vones, lacc[1], 0, 0, 0);
#pragma unroll
        for (int dn = 0; dn < 8; ++dn) {
          const bx8 vf = *(const bx8*)(vbase + (size_t)(dn * 16 + lr) * 2048 + kv0 +
                                       ks2 * 32 + lg * 8);
          oacc[0][dn] =
              __builtin_amdgcn_mfma_f32_16x16x32_bf16(pf0, vf, oacc[0][dn], 0, 0, 0);
          oacc[1][dn] =
              __builtin_amdgcn_mfma_f32_16x16x32_bf16(pf1, vf, oacc[1][dn], 0, 0, 0);
        }
      }
      __builtin_amdgcn_s_setprio(0);
    }
    __builtin_amdgcn_s_barrier();  // all waves done reading Ks[cur]
    asm volatile("" ::: "memory");
  }

  if (single) {
    float rl[2][4];
#pragma unroll
    for (int m = 0; m < 2; ++m)
#pragma unroll
      for (int j = 0; j < 4; ++j) rl[m][j] = 1.0f / lacc[m][j];
#pragma unroll
    for (int m = 0; m < 2; ++m)
#pragma unroll
      for (int dn = 0; dn < 8; ++dn)
#pragma unroll
        for (int j = 0; j < 4; ++j) {
          const int row = qt * 128 + w * 32 + m * 16 + lg * 4 + j;
          ctx[(size_t)(b * 2048 + row) * 2048 + h * 128 + dn * 16 + lr] =
              __float2bfloat16(oacc[m][dn][j] * rl[m][j]);
        }
  } else {
    // disjoint plain-store partials (each element written exactly once)
    float* Op = (u < 8) ? O0 : O1;
    float* lp = (u < 8) ? l0 : l1;
    float* obase =
        Op + (((size_t)(b * 16 + h)) * 1024 + (qt * 128 - 1024 + w * 32)) * 128;
#pragma unroll
    for (int m = 0; m < 2; ++m)
#pragma unroll
      for (int dn = 0; dn < 8; ++dn)
#pragma unroll
        for (int j = 0; j < 4; ++j)
          obase[(m * 16 + lg * 4 + j) * 128 + dn * 16 + lr] = oacc[m][dn][j];
    if (lr == 0) {
      float* lbase =
          lp + ((size_t)(b * 16 + h)) * 1024 + (qt * 128 - 1024 + w * 32);
#pragma unroll
      for (int m = 0; m < 2; ++m)
#pragma unroll
        for (int j = 0; j < 4; ++j) lbase[m * 16 + lg * 4 + j] = lacc[m][j];
    }
  }
}

// ----------------------- combine split rows: ctx = (O0+O1)/(l0+l1), s>=1024
__global__ __launch_bounds__(256) void k_comb(const float* __restrict__ O0,
                                              const float* __restrict__ O1,
                                              const float* __restrict__ l0,
                                              const float* __restrict__ l1,
                                              bf16* __restrict__ ctx) {
  const int idx = blockIdx.x * 256 + threadIdx.x;  // 524288 threads x 8 floats
  const size_t base = (size_t)idx * 8;
  const size_t rowi = base >> 7;  // (b*16+h)*1024 + (s-1024)
  const float rl = 1.0f / (l0[rowi] + l1[rowi]);
  const float4 a0 = *(const float4*)&O0[base];
  const float4 b0 = *(const float4*)&O0[base + 4];
  const float4 a1 = *(const float4*)&O1[base];
  const float4 b1 = *(const float4*)&O1[base + 4];
  const int d = (int)(base & 127);
  const int s = (int)(rowi & 1023);
  const int bh = (int)(rowi >> 10);
  const int b = bh >> 4, h = bh & 15;
  bf16 o[8] = {__float2bfloat16((a0.x + a1.x) * rl), __float2bfloat16((a0.y + a1.y) * rl),
               __float2bfloat16((a0.z + a1.z) * rl), __float2bfloat16((a0.w + a1.w) * rl),
               __float2bfloat16((b0.x + b1.x) * rl), __float2bfloat16((b0.y + b1.y) * rl),
               __float2bfloat16((b0.z + b1.z) * rl), __float2bfloat16((b0.w + b1.w) * rl)};
  bf16* p = ctx + (size_t)(b * 2048 + 1024 + s) * 2048 + h * 128 + d;
  *(ushort4*)p = *(ushort4*)o;
  *(ushort4*)(p + 4) = *(ushort4*)(o + 4);
}

// ------------------------------------------------------------------- launcher
extern "C" void kernel_launch(void* const* d_in, const int* in_sizes, int n_in,
                              void* d_out, int out_size, void* d_ws, size_t ws_size,
                              hipStream_t stream) {
  const float* x = (const float*)d_in[0];
  const float* Wqkv = (const float*)d_in[1];
  const float* bqkv = (const float*)d_in[2];
  const float* Wout = (const float*)d_in[3];
  const float* bout = (const float*)d_in[4];
  float* out = (float*)d_out;

  char* ws = (char*)d_ws;
  bf16* xb    = (bf16*)(ws + 0);          // 16 MiB (dead after QKV GEMM)
  bf16* wqkvT = (bf16*)(ws + 16777216);   // 24 MiB (dead after QKV GEMM)
  bf16* woutT = (bf16*)(ws + 41943040);   // 8 MiB
  bf16* qkvb  = (bf16*)(ws + 50331648);   // 48 MiB (V region unused now)
  bf16* vTb   = (bf16*)(ws + 100663296);  // 16 MiB
  bf16* ctxb  = (bf16*)(ws + 117440512);  // 16 MiB
  float2* csT = (float2*)(ws + 134217728); // 1 MiB interleaved cos/sin
  // split-KV partials overlap the dead xb/wqkvT regions:
  float* O0 = (float*)(ws + 0);               // 16 MiB
  float* O1 = (float*)(ws + 16777216);        // 16 MiB
  float* l0 = (float*)(ws + 33554432);        // 128 KiB
  float* l1 = (float*)(ws + 33685504);        // 128 KiB

  k_ropetab<<<512, 256, 0, stream>>>(csT);
  k_cast<<<8192, 256, 0, stream>>>(x, xb, 2097152);
  k_tcast<<<dim3(192, 64), dim3(32, 8), 0, stream>>>(Wqkv, wqkvT, 2048, 6144);
  k_tcast<<<dim3(64, 64), dim3(32, 8), 0, stream>>>(Wout, woutT, 2048, 2048);
  // QKV = x @ Wqkv + b: register-pair RoPE epilogue; V written transposed
  k_gemm_bt<1><<<dim3(48, 32), 256, 0, stream>>>(xb, wqkvT, bqkv, qkvb, vTb,
                                                 4096, 6144, 2048, 1, csT);
  // split-KV flash attention: 768 blocks, heavy-first issue order
  k_attn2<<<768, 256, 0, stream>>>(qkvb, vTb, ctxb, O0, O1, l0, l1);
  k_comb<<<2048, 256, 0, stream>>>(O0, O1, l0, l1, ctxb);
  // out = ctx @ Wout + bout (fp32 out)
  k_gemm_bt<0><<<dim3(16, 32), 256, 0, stream>>>(ctxb, woutT, bout, out, nullptr,
                                                 4096, 2048, 2048, 0, csT);
}

// Round 20
// 302.958 us; speedup vs baseline: 1.1700x; 1.0059x over previous
//
#include <hip/hip_runtime.h>
#include <hip/hip_bf16.h>

typedef __attribute__((ext_vector_type(4))) float fx4;
typedef __attribute__((ext_vector_type(8))) short bx8;
typedef __hip_bfloat16 bf16;

#define GLD16(dst, src)                                                        \
  __builtin_amdgcn_global_load_lds(                                            \
      (__attribute__((address_space(1))) void*)(src),                          \
      (__attribute__((address_space(3))) void*)(dst), 16, 0, 0)

__device__ inline float bf2f(short s_) {
  unsigned int u = ((unsigned int)(unsigned short)s_) << 16;
  float f;
  __builtin_memcpy(&f, &u, 4);
  return f;
}
__device__ inline short f2bf(float f) {
  __hip_bfloat16 h = __float2bfloat16(f);
  short r;
  __builtin_memcpy(&r, &h, 2);
  return r;
}

#define ATT_SL2E 0.12751740f  // (1/sqrt(128)) * log2(e), pre-folded into Q

// ---------------------------------------------------------------- cast x->bf16
__global__ __launch_bounds__(256) void k_cast(const float* __restrict__ in,
                                              bf16* __restrict__ out, int n4) {
  int i = blockIdx.x * 256 + threadIdx.x;
  if (i >= n4) return;
  float4 v = reinterpret_cast<const float4*>(in)[i];
  bf16 t[4] = {__float2bfloat16(v.x), __float2bfloat16(v.y),
               __float2bfloat16(v.z), __float2bfloat16(v.w)};
  reinterpret_cast<ushort4*>(out)[i] = *reinterpret_cast<ushort4*>(t);
}

// ------------------------------------------- transpose-cast fp32 RxC -> bf16 CxR
__global__ void k_tcast(const float* __restrict__ in, bf16* __restrict__ out,
                        int R, int C) {
  __shared__ float tile[32][33];
  int c0 = blockIdx.x * 32, r0 = blockIdx.y * 32;
  int tx = threadIdx.x, ty = threadIdx.y;
#pragma unroll
  for (int j = 0; j < 4; ++j)
    tile[ty + j * 8][tx] = in[(size_t)(r0 + ty + j * 8) * C + c0 + tx];
  __syncthreads();
#pragma unroll
  for (int j = 0; j < 4; ++j)
    out[(size_t)(c0 + ty + j * 8) * R + r0 + tx] =
        __float2bfloat16(tile[tx][ty + j * 8]);
}

// ------------------------- rope cos/sin table (packed bf16: halves L2 refetch)
__global__ __launch_bounds__(256) void k_ropetab(ushort2* __restrict__ csT) {
  int idx = blockIdx.x * 256 + threadIdx.x;  // 2048*64
  int t = idx >> 6, i = idx & 63;
  float inv = expf(-logf(10000.0f) * (float)i * (1.0f / 64.0f));
  float fr = (float)t * inv;
  ushort2 cs;
  cs.x = (unsigned short)f2bf(cosf(fr));
  cs.y = (unsigned short)f2bf(sinf(fr));
  csT[idx] = cs;
}

// --------------------- 128x128 GEMM (m97 structure, proven ~900 TF) ----------
// ROPE=1: compile-time column map col(n) = wc*32 + (n&1)*16 + (n>>1)*64 + lr
// -> each thread holds the rope pair (c, c+64) in acc[m][n], acc[m][n|2].
// V-blocks (n0>=4096): write DIRECTLY transposed to vT[b,h,d,s].
template <int ROPE>
__global__ __launch_bounds__(256) void k_gemm_bt(
    const bf16* __restrict__ A, const bf16* __restrict__ BT,
    const float* __restrict__ bias, void* __restrict__ Cp,
    bf16* __restrict__ vTout, int M, int N, int K, int out_bf16,
    const ushort2* __restrict__ csT) {
  __shared__ __align__(16) bf16 As[128 * 64];
  __shared__ __align__(16) bf16 Bs[128 * 64];
  const int tid = threadIdx.x;
  const int m0 = blockIdx.y * 128, n0 = blockIdx.x * 128;
  const int lane = tid & 63, w = tid >> 6;
  const int lr = lane & 15, lg = lane >> 4;
  const int wr = w >> 1, wc = w & 1;
  const int colbase = ROPE ? (wc * 32 + lr) : (wc * 64 + lr);
#define COLOF(n) (ROPE ? (colbase + ((n)&1) * 16 + ((n) >> 1) * 64) : (colbase + (n)*16))

  fx4 acc[4][4];
#pragma unroll
  for (int m = 0; m < 4; ++m)
#pragma unroll
    for (int n = 0; n < 4; ++n) acc[m][n] = (fx4)(0.0f);

  for (int kt = 0; kt < K; kt += 64) {
#pragma unroll
    for (int q = 0; q < 4; ++q) {
      const int slot = q * 256 + tid;
      const int row = slot >> 3, u = slot & 7;
      const int us = (u ^ (row & 7)) * 8;
      GLD16(&As[slot * 8], A + (size_t)(m0 + row) * K + kt + us);
      GLD16(&Bs[slot * 8], BT + (size_t)(n0 + row) * K + kt + us);
    }
    __syncthreads();
#pragma unroll
    for (int ks = 0; ks < 2; ++ks) {
      bx8 af[4], bf[4];
#pragma unroll
      for (int m = 0; m < 4; ++m) {
        const int r = wr * 64 + m * 16 + lr;
        const int u = ((ks * 4 + lg) ^ (lr & 7)) * 8;
        af[m] = *(const bx8*)&As[r * 64 + u];
      }
#pragma unroll
      for (int n = 0; n < 4; ++n) {
        const int r = COLOF(n);
        const int u = ((ks * 4 + lg) ^ (lr & 7)) * 8;
        bf[n] = *(const bx8*)&Bs[r * 64 + u];
      }
#pragma unroll
      for (int m = 0; m < 4; ++m)
#pragma unroll
        for (int n = 0; n < 4; ++n)
          acc[m][n] =
              __builtin_amdgcn_mfma_f32_16x16x32_bf16(af[m], bf[n], acc[m][n], 0, 0, 0);
    }
    __syncthreads();
  }

  float bv[4];
#pragma unroll
  for (int n = 0; n < 4; ++n) bv[n] = bias[n0 + COLOF(n)];

  if (ROPE) {
    bf16* Cb = (bf16*)Cp;
    if (n0 < 4096) {
      // register-pair rope: n in {0,1} holds col c, n|2 holds col c+64
      const float sc = (n0 < 2048) ? ATT_SL2E : 1.0f;  // q gets softmax scale
#pragma unroll
      for (int m = 0; m < 4; ++m)
#pragma unroll
        for (int n = 0; n < 2; ++n) {
          const int c = wc * 32 + n * 16 + lr;  // in [0,64)
#pragma unroll
          for (int j = 0; j < 4; ++j) {
            const int row = m0 + wr * 64 + m * 16 + lg * 4 + j;
            const int s = row & 2047;
            const ushort2 cs = csT[s * 64 + c];
            const float co = bf2f((short)cs.x), si = bf2f((short)cs.y);
            const float t1 = acc[m][n][j] + bv[n];
            const float t2 = acc[m][n | 2][j] + bv[n | 2];
            Cb[(size_t)row * N + n0 + c] =
                __float2bfloat16((t1 * co - t2 * si) * sc);
            Cb[(size_t)row * N + n0 + c + 64] =
                __float2bfloat16((t1 * si + t2 * co) * sc);
          }
        }
    } else {
      // V-block: write transposed to vT[(b*16+h)*128 + d][s], ushort4 over j
      const int h = (n0 - 4096) >> 7;      // head
      const int bq = m0 >> 11;             // batch (rows of a block share b)
      const int s0 = (m0 & 2047) + wr * 64;
#pragma unroll
      for (int m = 0; m < 4; ++m)
#pragma unroll
        for (int n = 0; n < 4; ++n) {
          const int d = COLOF(n);
          const int s = s0 + m * 16 + lg * 4;
          bf16 o4[4] = {__float2bfloat16(acc[m][n][0] + bv[n]),
                        __float2bfloat16(acc[m][n][1] + bv[n]),
                        __float2bfloat16(acc[m][n][2] + bv[n]),
                        __float2bfloat16(acc[m][n][3] + bv[n])};
          *(ushort4*)&vTout[((size_t)((bq * 16 + h) * 128 + d)) * 2048 + s] =
              *(ushort4*)o4;
        }
    }
    return;
  }

#pragma unroll
  for (int m = 0; m < 4; ++m)
#pragma unroll
    for (int n = 0; n < 4; ++n) {
      const int col = n0 + COLOF(n);
#pragma unroll
      for (int j = 0; j < 4; ++j) {
        const int row = m0 + wr * 64 + m * 16 + lg * 4 + j;
        const float v = acc[m][n][j] + bv[n];
        if (out_bf16)
          ((bf16*)Cp)[(size_t)row * N + col] = __float2bfloat16(v);
        else
          ((float*)Cp)[(size_t)row * N + col] = v;
      }
    }
#undef COLOF
}

// ------------------------------------------------------------- flash attention
// Split-KV, disjoint plain-store partials. KVBLK=64 dbuf + vmcnt(4).
// 48KB LDS -> 3 blocks/CU. Heavy blocks issued first (R14 lesson). Inline V
// loads in PV (R17 lesson: register prefetch breaks the compiler's schedule).
__global__ __launch_bounds__(256, 2) void k_attn2(
    const bf16* __restrict__ qkv, const bf16* __restrict__ vT,
    bf16* __restrict__ ctx, float* __restrict__ O0, float* __restrict__ O1,
    float* __restrict__ l0, float* __restrict__ l1) {
  __shared__ __align__(16) bf16 Ks[2][64 * 128];
  __shared__ __align__(16) bf16 Ps[4][32 * 64];
  const int tid = threadIdx.x;
  const int lane = tid & 63, w = tid >> 6;
  const int lr = lane & 15, lg = lane >> 4;
  const int bid = blockIdx.x;
  const int u = bid >> 5, bh = bid & 31;
  const int b = bh >> 4, h = bh & 15;
  int qt, t0, t1;                    // t in units of 64 kv
  if (u < 8) {            // chunk0 of qt=8..15 : 16 tiles (kv 0..1023)
    qt = 8 + u; t0 = 0; t1 = 16;
  } else if (u < 16) {    // chunk1 of qt=15..8 : 2qt-14 tiles (kv 1024..)
    qt = 23 - u; t0 = 16; t1 = 2 * qt + 2;
  } else {                // full row qt=7..0 DESCENDING : 2qt+2 tiles
    qt = 23 - u; t0 = 0; t1 = 2 * qt + 2;
  }
  const int single = (u >= 16);
  const int nt = t1 - t0;

  const bf16* kbase = qkv + (size_t)b * 2048 * 6144 + 2048 + h * 128;
  const bf16* vbase = vT + (size_t)(b * 16 + h) * 128 * 2048;

  auto STAGE = [&](int bufi, int kt) {
    const int kv0 = kt * 64;
#pragma unroll
    for (int q = 0; q < 4; ++q) {
      const int slot = q * 256 + tid;
      const int row = slot >> 4, uu = slot & 15;
      GLD16(&Ks[bufi][slot * 8],
            kbase + (size_t)(kv0 + row) * 6144 + ((uu ^ (row & 15)) * 8));
    }
  };

  // Q fragments: 32 rows/wave (Q already has SL2E folded in)
  const bf16* qbase =
      qkv + (size_t)(b * 2048 + qt * 128 + w * 32) * 6144 + h * 128;
  bx8 qf[2][4];
#pragma unroll
  for (int m = 0; m < 2; ++m)
#pragma unroll
    for (int ks = 0; ks < 4; ++ks)
      qf[m][ks] = *(const bx8*)(qbase + (size_t)(m * 16 + lr) * 6144 + ks * 32 + lg * 8);

  bx8 vones;
#pragma unroll
  for (int e = 0; e < 8; ++e) vones[e] = (short)0x3F80;  // bf16 1.0

  fx4 oacc[2][8], lacc[2];
#pragma unroll
  for (int m = 0; m < 2; ++m) {
    lacc[m] = (fx4)(0.0f);
#pragma unroll
    for (int d = 0; d < 8; ++d) oacc[m][d] = (fx4)(0.0f);
  }

  const int qrow0 = qt * 128 + w * 32;

  STAGE(0, t0);
  for (int i = 0; i < nt; ++i) {
    const int kt = t0 + i;
    const int cur = i & 1;
    if (i + 1 < nt) {
      STAGE(cur ^ 1, kt + 1);
      asm volatile("s_waitcnt vmcnt(4)" ::: "memory");
    } else {
      asm volatile("s_waitcnt vmcnt(0)" ::: "memory");
    }
    __builtin_amdgcn_s_barrier();
    asm volatile("" ::: "memory");

    const int kv0 = kt * 64;
    if (kv0 <= qrow0 + 31) {  // else wave fully masked (barriers stay outside)
      // ---- QK^T over this 64-kv tile (result already in log2 units)
      fx4 sacc[2][4];
#pragma unroll
      for (int n = 0; n < 4; ++n) {
        sacc[0][n] = (fx4)(0.0f);
        sacc[1][n] = (fx4)(0.0f);
      }
      __builtin_amdgcn_s_setprio(1);
#pragma unroll
      for (int n = 0; n < 4; ++n) {
        const int r = n * 16 + lr;
#pragma unroll
        for (int ks = 0; ks < 4; ++ks) {
          const bx8 kf = *(const bx8*)&Ks[cur][r * 128 + (((ks * 4 + lg) ^ lr) * 8)];
          sacc[0][n] =
              __builtin_amdgcn_mfma_f32_16x16x32_bf16(qf[0][ks], kf, sacc[0][n], 0, 0, 0);
          sacc[1][n] =
              __builtin_amdgcn_mfma_f32_16x16x32_bf16(qf[1][ks], kf, sacc[1][n], 0, 0, 0);
        }
      }
      __builtin_amdgcn_s_setprio(0);

      // ---- static-max softmax: p = exp2(min(v, 60)); masked -> 0
      const bool needmask = (kv0 + 63) > qrow0;  // wave-uniform
#pragma unroll
      for (int n = 0; n < 4; ++n) {
        const int kvi = kv0 + n * 16 + lr;
#pragma unroll
        for (int m = 0; m < 2; ++m)
#pragma unroll
          for (int j = 0; j < 4; ++j) {
            float v = sacc[m][n][j];
            if (needmask) {
              const int qi = qrow0 + m * 16 + lg * 4 + j;
              if (kvi > qi) v = -200.0f;
            }
            const float p = exp2f(fminf(v, 60.0f));
            const int r = m * 16 + lg * 4 + j, c = n * 16 + lr;
            const int c2 = (c & 7) | (((c >> 3) ^ (r & 7)) << 3);
            Ps[w][r * 64 + c2] = __float2bfloat16(p);
          }
      }

      // ---- PV (V direct from global, L2-resident) + row-sum via ones-MFMA
      __builtin_amdgcn_s_setprio(1);
#pragma unroll
      for (int ks2 = 0; ks2 < 2; ++ks2) {
        const int uu = ((ks2 * 4 + lg) ^ (lr & 7)) * 8;
        const bx8 pf0 = *(const bx8*)&Ps[w][(0 * 16 + lr) * 64 + uu];
        const bx8 pf1 = *(const bx8*)&Ps[w][(1 * 16 + lr) * 64 + uu];
        lacc[0] = __builtin_amdgcn_mfma_f32_16x16x32_bf16(pf0, vones, lacc[0], 0, 0, 0);
        lacc[1] = __builtin_amdgcn_mfma_f32_16x16x32_bf16(pf1, vones, lacc[1], 0, 0, 0);
#pragma unroll
        for (int dn = 0; dn < 8; ++dn) {
          const bx8 vf = *(const bx8*)(vbase + (size_t)(dn * 16 + lr) * 2048 + kv0 +
                                       ks2 * 32 + lg * 8);
          oacc[0][dn] =
              __builtin_amdgcn_mfma_f32_16x16x32_bf16(pf0, vf, oacc[0][dn], 0, 0, 0);
          oacc[1][dn] =
              __builtin_amdgcn_mfma_f32_16x16x32_bf16(pf1, vf, oacc[1][dn], 0, 0, 0);
        }
      }
      __builtin_amdgcn_s_setprio(0);
    }
    __builtin_amdgcn_s_barrier();  // all waves done reading Ks[cur]
    asm volatile("" ::: "memory");
  }

  if (single) {
    float rl[2][4];
#pragma unroll
    for (int m = 0; m < 2; ++m)
#pragma unroll
      for (int j = 0; j < 4; ++j) rl[m][j] = 1.0f / lacc[m][j];
#pragma unroll
    for (int m = 0; m < 2; ++m)
#pragma unroll
      for (int dn = 0; dn < 8; ++dn)
#pragma unroll
        for (int j = 0; j < 4; ++j) {
          const int row = qt * 128 + w * 32 + m * 16 + lg * 4 + j;
          ctx[(size_t)(b * 2048 + row) * 2048 + h * 128 + dn * 16 + lr] =
              __float2bfloat16(oacc[m][dn][j] * rl[m][j]);
        }
  } else {
    // disjoint plain-store partials (each element written exactly once)
    float* Op = (u < 8) ? O0 : O1;
    float* lp = (u < 8) ? l0 : l1;
    float* obase =
        Op + (((size_t)(b * 16 + h)) * 1024 + (qt * 128 - 1024 + w * 32)) * 128;
#pragma unroll
    for (int m = 0; m < 2; ++m)
#pragma unroll
      for (int dn = 0; dn < 8; ++dn)
#pragma unroll
        for (int j = 0; j < 4; ++j)
          obase[(m * 16 + lg * 4 + j) * 128 + dn * 16 + lr] = oacc[m][dn][j];
    if (lr == 0) {
      float* lbase =
          lp + ((size_t)(b * 16 + h)) * 1024 + (qt * 128 - 1024 + w * 32);
#pragma unroll
      for (int m = 0; m < 2; ++m)
#pragma unroll
        for (int j = 0; j < 4; ++j) lbase[m * 16 + lg * 4 + j] = lacc[m][j];
    }
  }
}

// ----------------------- combine split rows: ctx = (O0+O1)/(l0+l1), s>=1024
__global__ __launch_bounds__(256) void k_comb(const float* __restrict__ O0,
                                              const float* __restrict__ O1,
                                              const float* __restrict__ l0,
                                              const float* __restrict__ l1,
                                              bf16* __restrict__ ctx) {
  const int idx = blockIdx.x * 256 + threadIdx.x;  // 524288 threads x 8 floats
  const size_t base = (size_t)idx * 8;
  const size_t rowi = base >> 7;  // (b*16+h)*1024 + (s-1024)
  const float rl = 1.0f / (l0[rowi] + l1[rowi]);
  const float4 a0 = *(const float4*)&O0[base];
  const float4 b0 = *(const float4*)&O0[base + 4];
  const float4 a1 = *(const float4*)&O1[base];
  const float4 b1 = *(const float4*)&O1[base + 4];
  const int d = (int)(base & 127);
  const int s = (int)(rowi & 1023);
  const int bh = (int)(rowi >> 10);
  const int b = bh >> 4, h = bh & 15;
  bf16 o[8] = {__float2bfloat16((a0.x + a1.x) * rl), __float2bfloat16((a0.y + a1.y) * rl),
               __float2bfloat16((a0.z + a1.z) * rl), __float2bfloat16((a0.w + a1.w) * rl),
               __float2bfloat16((b0.x + b1.x) * rl), __float2bfloat16((b0.y + b1.y) * rl),
               __float2bfloat16((b0.z + b1.z) * rl), __float2bfloat16((b0.w + b1.w) * rl)};
  bf16* p = ctx + (size_t)(b * 2048 + 1024 + s) * 2048 + h * 128 + d;
  *(ushort4*)p = *(ushort4*)o;
  *(ushort4*)(p + 4) = *(ushort4*)(o + 4);
}

// ------------------------------------------------------------------- launcher
extern "C" void kernel_launch(void* const* d_in, const int* in_sizes, int n_in,
                              void* d_out, int out_size, void* d_ws, size_t ws_size,
                              hipStream_t stream) {
  const float* x = (const float*)d_in[0];
  const float* Wqkv = (const float*)d_in[1];
  const float* bqkv = (const float*)d_in[2];
  const float* Wout = (const float*)d_in[3];
  const float* bout = (const float*)d_in[4];
  float* out = (float*)d_out;

  char* ws = (char*)d_ws;
  bf16* xb    = (bf16*)(ws + 0);          // 16 MiB (dead after QKV GEMM)
  bf16* wqkvT = (bf16*)(ws + 16777216);   // 24 MiB (dead after QKV GEMM)
  bf16* woutT = (bf16*)(ws + 41943040);   // 8 MiB
  bf16* qkvb  = (bf16*)(ws + 50331648);   // 48 MiB (V region unused now)
  bf16* vTb   = (bf16*)(ws + 100663296);  // 16 MiB
  bf16* ctxb  = (bf16*)(ws + 117440512);  // 16 MiB
  ushort2* csT = (ushort2*)(ws + 134217728); // 512 KiB packed bf16 cos/sin
  // split-KV partials overlap the dead xb/wqkvT regions:
  float* O0 = (float*)(ws + 0);               // 16 MiB
  float* O1 = (float*)(ws + 16777216);        // 16 MiB
  float* l0 = (float*)(ws + 33554432);        // 128 KiB
  float* l1 = (float*)(ws + 33685504);        // 128 KiB

  k_ropetab<<<512, 256, 0, stream>>>(csT);
  k_cast<<<8192, 256, 0, stream>>>(x, xb, 2097152);
  k_tcast<<<dim3(192, 64), dim3(32, 8), 0, stream>>>(Wqkv, wqkvT, 2048, 6144);
  k_tcast<<<dim3(64, 64), dim3(32, 8), 0, stream>>>(Wout, woutT, 2048, 2048);
  // QKV = x @ Wqkv + b: register-pair RoPE epilogue; V written transposed
  k_gemm_bt<1><<<dim3(48, 32), 256, 0, stream>>>(xb, wqkvT, bqkv, qkvb, vTb,
                                                 4096, 6144, 2048, 1, csT);
  // split-KV flash attention: 768 blocks, heavy-first issue order
  k_attn2<<<768, 256, 0, stream>>>(qkvb, vTb, ctxb, O0, O1, l0, l1);
  k_comb<<<2048, 256, 0, stream>>>(O0, O1, l0, l1, ctxb);
  // out = ctx @ Wout + bout (fp32 out)
  k_gemm_bt<0><<<dim3(16, 32), 256, 0, stream>>>(ctxb, woutT, bout, out, nullptr,
                                                 4096, 2048, 2048, 0, csT);
}